// Round 20
// baseline (129.660 us; speedup 1.0000x reference)
//
#include <hip/hip_runtime.h>
#include <hip/hip_bf16.h>

// Problem constants
#define NB   32      // batch
#define NC   24      // image channels
#define ND   12      // spatial
#define NN   144     // ND*ND objects
#define QD   11
#define GH   256
#define FOUT 10

typedef unsigned short u16;
typedef _Float16 f16;
typedef __attribute__((ext_vector_type(8))) _Float16 f16x8;
typedef __attribute__((ext_vector_type(4))) float f32x4;

// Workspace layout (u16 units unless noted):
//   Lqh  u16 [32][144][256]  off 0          (= L + q@Wg1_q + bg1, f16)
//   Rh   u16 [32][144][256]  off 1179648
//   Bswz u16 [128][64][8]    off 2359296    (16x16x32 B-fragment order, f16)
//   S    f32 [32][256]       byte-off 4849664
#define LQ_U16  0
#define R_U16   1179648
#define BS_U16  2359296
#define S_BYTE  4849664

__device__ inline u16 f2h(float f) {
  f16 h = (f16)f;
  return *reinterpret_cast<u16*>(&h);
}

// ---------------------------------------------------------------------------
// prep v2 (r17-proven): Wg1 in registers; blocks [0,256) projections (f16
// out), blocks [256,512): Wg2 -> f16 B-fragment swizzle + zero S.
// ---------------------------------------------------------------------------
__global__ __launch_bounds__(256) void prep(const float* __restrict__ image,
                                            const float* __restrict__ question,
                                            const float* __restrict__ Wg1,
                                            const float* __restrict__ bg1,
                                            const float* __restrict__ Wg2,
                                            u16* __restrict__ Lq,
                                            u16* __restrict__ R,
                                            float* __restrict__ S,
                                            u16* __restrict__ Bswz) {
  int blk = blockIdx.x;
  int h   = threadIdx.x;
  if (blk < 256) {
    const int quarter = blk & 3;
    const int b       = (blk >> 2) & 31;
    const int which   = blk >> 7;
    float Wl[NC + 2];
#pragma unroll
    for (int r = 0; r < NC + 2; ++r)
      Wl[r] = Wg1[(which * (NC + 2) + r) * GH + h];
    float qacc = 0.f;
    if (which == 0) {
      qacc = bg1[h];
#pragma unroll
      for (int tq = 0; tq < QD; ++tq)
        qacc += question[b * QD + tq] * Wg1[(2 * (NC + 2) + tq) * GH + h];
    }
    const float* img = image + b * (NC * NN);
    u16* dst = (which == 0 ? Lq : R) + b * NN * GH + h;
    const float inv = 1.0f / (ND - 1);
#pragma unroll 4
    for (int p = quarter * 36; p < quarter * 36 + 36; ++p) {
      float acc = qacc;
#pragma unroll
      for (int c = 0; c < NC; ++c) acc += img[c * NN + p] * Wl[c];
      int i = p / ND, j = p - i * ND;
      acc += (j * inv) * Wl[24];
      acc += (i * inv) * Wl[25];
      dst[p * GH] = f2h(acc);
    }
  } else {
    int tid = (blk - 256) * 256 + h;   // 0..65535
    int e   = tid & 7;
    int l   = (tid >> 3) & 63;
    int fid = tid >> 9;
    int kt  = fid >> 4, nt = fid & 15;
    int k = kt * 32 + ((l >> 4) << 3) + e;
    int n = (nt << 4) + (l & 15);
    Bswz[tid] = f2h(Wg2[k * GH + n]);
    if (tid < NB * GH) S[tid] = 0.f;
  }
}

// ---------------------------------------------------------------------------
// MFMA pair GEMM v20 = v19 (f16, phase-split, 98 us) + latency fixes:
//  (a) T14 R-prefetch: Rpre[8] (32 VGPR) for tile t+1 issued right after the
//      build->mma barrier -> R's L2 latency hides under the ~5k-cyc mma
//      phase instead of stalling the build (measured ~82k cyc/CU stall).
//  (b) 2-deep B ring (bcur/bnxt, wraps across tiles): B group for kt+1
//      issues before kt's MFMAs (depth-0 was leaving mma waves on vmcnt).
// Arch regs ~105 <= 128 (acc in AGPRs; v15's failure was its 128-reg
// persistent B, not the prefetch). Everything else identical to v19.
// ---------------------------------------------------------------------------
__global__ __launch_bounds__(512, 2) void pair_gemm(const u16* __restrict__ Lq,
                                                    const u16* __restrict__ R,
                                                    const u16* __restrict__ Bswz,
                                                    const float* __restrict__ bg2,
                                                    float* __restrict__ S) {
  const int bid = blockIdx.x;          // 0..511
  const int xcd = bid & 7;
  const int idx = bid >> 3;            // 0..63
  const int b   = xcd * 4 + (idx >> 4);
  const int bi  = idx & 15;            // 16 blocks per batch, 162 tiles
  const int t0  = bi * 10 + (bi < 2 ? bi : 2);
  const int cnt = 10 + (bi < 2 ? 1 : 0);

  // [kt 8][mf 8][lane 64][8 f16] = 64 KB
  __shared__ __align__(16) u16 As[8 * 8 * 64 * 8];

  const int t = threadIdx.x;
  const int w = t >> 6, l = t & 63;
  const int wn = w & 3, wm = w >> 2;
  // builder role: row t>>2 (0..127), k-octet t&3
  const int brow = t >> 2;
  const int oc   = t & 3;
  const int mf_w   = brow >> 4;                              // 0..7
  const int lane_w = ((brow & 15) | (oc << 4)) ^ (oc << 1);  // 2-way (free)
  const int lane_r = l ^ (((l >> 4) & 3) << 1);

  const u16* Lbase = Lq + b * NN * GH;
  const u16* Rbase = R + b * NN * GH;
  const u16* Bl    = Bswz + l * 8;

  float bgv[4];
#pragma unroll
  for (int nt = 0; nt < 4; ++nt)
    bgv[nt] = bg2[(wn << 6) + (nt << 4) + (l & 15)];
  float ssum[4] = {0.f, 0.f, 0.f, 0.f};

  // ---- prime R-prefetch for tile t0 (one-time exposed latency) ----
  int pj = (t0 * 128 + brow) % NN;
  f16x8 Rpre[8];
  {
    const u16* Rr = Rbase + pj * GH + oc * 8;
#pragma unroll
    for (int u = 0; u < 8; ++u)
      Rpre[u] = *(const f16x8*)(Rr + u * 32);
  }
  // ---- prime B ring: kt=0 group (B is tile-invariant) ----
  f16x8 bcur[4], bnxt[4];
#pragma unroll
  for (int nt = 0; nt < 4; ++nt)
    bcur[nt] = *(const f16x8*)(Bl + ((size_t)((wn << 2) | nt) << 9));

  for (int tt = 0; tt < cnt; ++tt) {
    // ---- build phase: consume Rpre regs + L (L1-hot: 1-2 rows/tile) ----
    {
      int p = (t0 + tt) * 128 + brow;
      int i = p / NN;
      const u16* Lr = Lbase + i * GH + oc * 8;
#pragma unroll
      for (int u = 0; u < 8; ++u) {
        f16x8 lv = *(const f16x8*)(Lr + u * 32);
        f16x8 s  = lv + Rpre[u];                        // v_pk_add_f16
        s = __builtin_elementwise_max(s, (f16x8)0.0f);  // v_pk_max_f16
        *(f16x8*)&As[((((u << 3) | mf_w) << 6) | lane_w) << 3] = s;
      }
    }
    __syncthreads();

    // ---- issue R-prefetch for tile tt+1 (lands during mma phase) ----
    if (tt + 1 < cnt) {
      pj = (pj >= 16) ? pj - 16 : pj + 128;   // j advances by 128 mod 144
      const u16* Rr = Rbase + pj * GH + oc * 8;
#pragma unroll
      for (int u = 0; u < 8; ++u)
        Rpre[u] = *(const f16x8*)(Rr + u * 32);
    }

    // ---- MFMA phase with 2-deep B ring ----
    f32x4 acc[4][4] = {};
#pragma unroll
    for (int kt = 0; kt < 8; ++kt) {
      // issue next kt's B group (wraps to group 0 for the next tile)
#pragma unroll
      for (int nt = 0; nt < 4; ++nt) {
        int fid = (((kt + 1) & 7) << 4) | (wn << 2) | nt;
        bnxt[nt] = *(const f16x8*)(Bl + ((size_t)fid << 9));
      }
      f16x8 af[4];
#pragma unroll
      for (int mf = 0; mf < 4; ++mf)
        af[mf] = *(const f16x8*)
            &As[((((kt << 3) | (wm << 2) | mf) << 6) | lane_r) << 3];
      __builtin_amdgcn_s_setprio(1);
#pragma unroll
      for (int mf = 0; mf < 4; ++mf)
#pragma unroll
        for (int nt = 0; nt < 4; ++nt)
          acc[mf][nt] = __builtin_amdgcn_mfma_f32_16x16x32_f16(
              af[mf], bcur[nt], acc[mf][nt], 0, 0, 0);
      __builtin_amdgcn_s_setprio(0);
#pragma unroll
      for (int nt = 0; nt < 4; ++nt) bcur[nt] = bnxt[nt];
    }
    // epilogue: fold relu(acc + bg2) into running sums
#pragma unroll
    for (int nt = 0; nt < 4; ++nt) {
      float s = 0.f;
#pragma unroll
      for (int mf = 0; mf < 4; ++mf)
#pragma unroll
        for (int r = 0; r < 4; ++r) {
          float v = acc[mf][nt][r] + bgv[nt];
          s += v > 0.f ? v : 0.f;
        }
      ssum[nt] += s;
    }
    __syncthreads();
  }

  // Final reduce: C/D col = l&15; shfl-reduce rows, one atomic per col slice
  float* Sb = S + b * GH;
#pragma unroll
  for (int nt = 0; nt < 4; ++nt) {
    float s = ssum[nt];
    s += __shfl_xor(s, 16, 64);
    s += __shfl_xor(s, 32, 64);
    if (l < 16) atomicAdd(&Sb[(wn << 6) + (nt << 4) + l], s);
  }
}

// ---------------------------------------------------------------------------
// Final f-MLP: out = relu(S@Wf1+bf1)@Wf2+bf2. One block per batch.
// ---------------------------------------------------------------------------
__global__ __launch_bounds__(256) void final_mlp(const float* __restrict__ S,
                                                 const float* __restrict__ Wf1,
                                                 const float* __restrict__ bf1,
                                                 const float* __restrict__ Wf2,
                                                 const float* __restrict__ bf2,
                                                 float* __restrict__ out) {
  __shared__ float sS[GH];
  __shared__ float oS[GH];
  int b = blockIdx.x, h = threadIdx.x;
  sS[h] = S[b * GH + h];
  __syncthreads();
  float acc = bf1[h];
#pragma unroll 8
  for (int k = 0; k < GH; ++k) acc += sS[k] * Wf1[k * GH + h];
  oS[h] = acc > 0.f ? acc : 0.f;
  __syncthreads();
  if (h < FOUT) {
    float o = bf2[h];
#pragma unroll 8
    for (int k = 0; k < GH; ++k) o += oS[k] * Wf2[k * FOUT + h];
    out[b * FOUT + h] = o;
  }
}

extern "C" void kernel_launch(void* const* d_in, const int* in_sizes, int n_in,
                              void* d_out, int out_size, void* d_ws, size_t ws_size,
                              hipStream_t stream) {
  const float* image    = (const float*)d_in[0];
  const float* question = (const float*)d_in[1];
  const float* Wg1      = (const float*)d_in[2];
  const float* bg1      = (const float*)d_in[3];
  const float* Wg2      = (const float*)d_in[4];
  const float* bg2      = (const float*)d_in[5];
  const float* Wf1      = (const float*)d_in[6];
  const float* bf1      = (const float*)d_in[7];
  const float* Wf2      = (const float*)d_in[8];
  const float* bf2      = (const float*)d_in[9];
  float* out = (float*)d_out;

  u16*   wsb  = (u16*)d_ws;
  u16*   Lqp  = wsb + LQ_U16;
  u16*   Rp   = wsb + R_U16;
  u16*   Bswz = wsb + BS_U16;
  float* Sp   = (float*)((char*)d_ws + S_BYTE);

  prep<<<512, 256, 0, stream>>>(image, question, Wg1, bg1, Wg2,
                                Lqp, Rp, Sp, Bswz);
  pair_gemm<<<512, 512, 0, stream>>>(Lqp, Rp, Bswz, bg2, Sp);
  final_mlp<<<NB, 256, 0, stream>>>(Sp, Wf1, bf1, Wf2, bf2, out);
}

// Round 21
// 129.397 us; speedup vs baseline: 1.0020x; 1.0020x over previous
//
#include <hip/hip_runtime.h>
#include <hip/hip_bf16.h>

// Problem constants
#define NB   32      // batch
#define NC   24      // image channels
#define ND   12      // spatial
#define NN   144     // ND*ND objects
#define QD   11
#define GH   256
#define FOUT 10

typedef unsigned short u16;
typedef _Float16 f16;
typedef __attribute__((ext_vector_type(8))) _Float16 f16x8;
typedef __attribute__((ext_vector_type(4))) float f32x4;

// Workspace layout (u16 units unless noted):
//   Lqh  u16 [32][144][256]  off 0          (= L + q@Wg1_q + bg1, f16)
//   Rh   u16 [32][144][256]  off 1179648
//   Bswz u16 [128][64][8]    off 2359296    (16x16x32 B-fragment order, f16)
//   S    f32 [32][256]       byte-off 4849664
#define LQ_U16  0
#define R_U16   1179648
#define BS_U16  2359296
#define S_BYTE  4849664

__device__ inline u16 f2h(float f) {
  f16 h = (f16)f;
  return *reinterpret_cast<u16*>(&h);
}

// ---------------------------------------------------------------------------
// prep v2 (r17-proven): Wg1 in registers; blocks [0,256) projections (f16
// out), blocks [256,512): Wg2 -> f16 B-fragment swizzle + zero S.
// ---------------------------------------------------------------------------
__global__ __launch_bounds__(256) void prep(const float* __restrict__ image,
                                            const float* __restrict__ question,
                                            const float* __restrict__ Wg1,
                                            const float* __restrict__ bg1,
                                            const float* __restrict__ Wg2,
                                            u16* __restrict__ Lq,
                                            u16* __restrict__ R,
                                            float* __restrict__ S,
                                            u16* __restrict__ Bswz) {
  int blk = blockIdx.x;
  int h   = threadIdx.x;
  if (blk < 256) {
    const int quarter = blk & 3;
    const int b       = (blk >> 2) & 31;
    const int which   = blk >> 7;
    float Wl[NC + 2];
#pragma unroll
    for (int r = 0; r < NC + 2; ++r)
      Wl[r] = Wg1[(which * (NC + 2) + r) * GH + h];
    float qacc = 0.f;
    if (which == 0) {
      qacc = bg1[h];
#pragma unroll
      for (int tq = 0; tq < QD; ++tq)
        qacc += question[b * QD + tq] * Wg1[(2 * (NC + 2) + tq) * GH + h];
    }
    const float* img = image + b * (NC * NN);
    u16* dst = (which == 0 ? Lq : R) + b * NN * GH + h;
    const float inv = 1.0f / (ND - 1);
#pragma unroll 4
    for (int p = quarter * 36; p < quarter * 36 + 36; ++p) {
      float acc = qacc;
#pragma unroll
      for (int c = 0; c < NC; ++c) acc += img[c * NN + p] * Wl[c];
      int i = p / ND, j = p - i * ND;
      acc += (j * inv) * Wl[24];
      acc += (i * inv) * Wl[25];
      dst[p * GH] = f2h(acc);
    }
  } else {
    int tid = (blk - 256) * 256 + h;   // 0..65535
    int e   = tid & 7;
    int l   = (tid >> 3) & 63;
    int fid = tid >> 9;
    int kt  = fid >> 4, nt = fid & 15;
    int k = kt * 32 + ((l >> 4) << 3) + e;
    int n = (nt << 4) + (l & 15);
    Bswz[tid] = f2h(Wg2[k * GH + n]);
    if (tid < NB * GH) S[tid] = 0.f;
  }
}

// ---------------------------------------------------------------------------
// MFMA pair GEMM v21 = v19 (f16 phase-split, 98 us) + T14 R-prefetch ONLY.
// The compiler already pipelines B loads within the unrolled mma loop up to
// its register headroom (m131-m141: explicit rings add nothing but register
// pressure -- v20's 17 MB spill). What it CANNOT do is hoist global loads
// across s_barrier: Rpre[8] (32 VGPR) for tile t+1, issued right after the
// build->mma barrier, lands during the ~5k-cyc mma phase and removes the
// build phase's R L2-latency exposure (the dominant measured stall).
// Build-phase live ~60 regs, mma-phase live ~90 + compiler headroom <= 128.
// Everything else identical to v19.
// ---------------------------------------------------------------------------
__global__ __launch_bounds__(512, 2) void pair_gemm(const u16* __restrict__ Lq,
                                                    const u16* __restrict__ R,
                                                    const u16* __restrict__ Bswz,
                                                    const float* __restrict__ bg2,
                                                    float* __restrict__ S) {
  const int bid = blockIdx.x;          // 0..511
  const int xcd = bid & 7;
  const int idx = bid >> 3;            // 0..63
  const int b   = xcd * 4 + (idx >> 4);
  const int bi  = idx & 15;            // 16 blocks per batch, 162 tiles
  const int t0  = bi * 10 + (bi < 2 ? bi : 2);
  const int cnt = 10 + (bi < 2 ? 1 : 0);

  // [kt 8][mf 8][lane 64][8 f16] = 64 KB
  __shared__ __align__(16) u16 As[8 * 8 * 64 * 8];

  const int t = threadIdx.x;
  const int w = t >> 6, l = t & 63;
  const int wn = w & 3, wm = w >> 2;
  // builder role: row t>>2 (0..127), k-octet t&3
  const int brow = t >> 2;
  const int oc   = t & 3;
  const int mf_w   = brow >> 4;                              // 0..7
  const int lane_w = ((brow & 15) | (oc << 4)) ^ (oc << 1);  // 2-way (free)
  const int lane_r = l ^ (((l >> 4) & 3) << 1);

  const u16* Lbase = Lq + b * NN * GH;
  const u16* Rbase = R + b * NN * GH;
  const u16* Bl    = Bswz + l * 8;

  float bgv[4];
#pragma unroll
  for (int nt = 0; nt < 4; ++nt)
    bgv[nt] = bg2[(wn << 6) + (nt << 4) + (l & 15)];
  float ssum[4] = {0.f, 0.f, 0.f, 0.f};

  // ---- prime R-prefetch for tile t0 (one-time exposed latency) ----
  int pj = (t0 * 128 + brow) % NN;
  f16x8 Rpre[8];
  {
    const u16* Rr = Rbase + pj * GH + oc * 8;
#pragma unroll
    for (int u = 0; u < 8; ++u)
      Rpre[u] = *(const f16x8*)(Rr + u * 32);
  }

  for (int tt = 0; tt < cnt; ++tt) {
    // ---- build phase: consume Rpre regs + L (L1-hot: 1-2 rows/tile) ----
    {
      int p = (t0 + tt) * 128 + brow;
      int i = p / NN;
      const u16* Lr = Lbase + i * GH + oc * 8;
#pragma unroll
      for (int u = 0; u < 8; ++u) {
        f16x8 lv = *(const f16x8*)(Lr + u * 32);
        f16x8 s  = lv + Rpre[u];                        // v_pk_add_f16
        s = __builtin_elementwise_max(s, (f16x8)0.0f);  // v_pk_max_f16
        *(f16x8*)&As[((((u << 3) | mf_w) << 6) | lane_w) << 3] = s;
      }
    }
    __syncthreads();

    // ---- issue R-prefetch for tile tt+1 (lands during mma phase;
    //      compiler cannot hoist these across the barrier itself) ----
    if (tt + 1 < cnt) {
      pj = (pj >= 16) ? pj - 16 : pj + 128;   // (j+128) mod 144
      const u16* Rr = Rbase + pj * GH + oc * 8;
#pragma unroll
      for (int u = 0; u < 8; ++u)
        Rpre[u] = *(const f16x8*)(Rr + u * 32);
    }

    // ---- MFMA phase (B loads compiler-pipelined across unrolled kt) ----
    f32x4 acc[4][4] = {};
#pragma unroll
    for (int kt = 0; kt < 8; ++kt) {
      f16x8 af[4];
#pragma unroll
      for (int mf = 0; mf < 4; ++mf)
        af[mf] = *(const f16x8*)
            &As[((((kt << 3) | (wm << 2) | mf) << 6) | lane_r) << 3];
      f16x8 bfr[4];
#pragma unroll
      for (int nt = 0; nt < 4; ++nt) {
        int fid = (kt << 4) | (wn << 2) | nt;
        bfr[nt] = *(const f16x8*)(Bl + ((size_t)fid << 9));
      }
      __builtin_amdgcn_s_setprio(1);
#pragma unroll
      for (int mf = 0; mf < 4; ++mf)
#pragma unroll
        for (int nt = 0; nt < 4; ++nt)
          acc[mf][nt] = __builtin_amdgcn_mfma_f32_16x16x32_f16(
              af[mf], bfr[nt], acc[mf][nt], 0, 0, 0);
      __builtin_amdgcn_s_setprio(0);
    }
    // epilogue: fold relu(acc + bg2) into running sums
#pragma unroll
    for (int nt = 0; nt < 4; ++nt) {
      float s = 0.f;
#pragma unroll
      for (int mf = 0; mf < 4; ++mf)
#pragma unroll
        for (int r = 0; r < 4; ++r) {
          float v = acc[mf][nt][r] + bgv[nt];
          s += v > 0.f ? v : 0.f;
        }
      ssum[nt] += s;
    }
    __syncthreads();
  }

  // Final reduce: C/D col = l&15; shfl-reduce rows, one atomic per col slice
  float* Sb = S + b * GH;
#pragma unroll
  for (int nt = 0; nt < 4; ++nt) {
    float s = ssum[nt];
    s += __shfl_xor(s, 16, 64);
    s += __shfl_xor(s, 32, 64);
    if (l < 16) atomicAdd(&Sb[(wn << 6) + (nt << 4) + l], s);
  }
}

// ---------------------------------------------------------------------------
// Final f-MLP: out = relu(S@Wf1+bf1)@Wf2+bf2. One block per batch.
// ---------------------------------------------------------------------------
__global__ __launch_bounds__(256) void final_mlp(const float* __restrict__ S,
                                                 const float* __restrict__ Wf1,
                                                 const float* __restrict__ bf1,
                                                 const float* __restrict__ Wf2,
                                                 const float* __restrict__ bf2,
                                                 float* __restrict__ out) {
  __shared__ float sS[GH];
  __shared__ float oS[GH];
  int b = blockIdx.x, h = threadIdx.x;
  sS[h] = S[b * GH + h];
  __syncthreads();
  float acc = bf1[h];
#pragma unroll 8
  for (int k = 0; k < GH; ++k) acc += sS[k] * Wf1[k * GH + h];
  oS[h] = acc > 0.f ? acc : 0.f;
  __syncthreads();
  if (h < FOUT) {
    float o = bf2[h];
#pragma unroll 8
    for (int k = 0; k < GH; ++k) o += oS[k] * Wf2[k * FOUT + h];
    out[b * FOUT + h] = o;
  }
}

extern "C" void kernel_launch(void* const* d_in, const int* in_sizes, int n_in,
                              void* d_out, int out_size, void* d_ws, size_t ws_size,
                              hipStream_t stream) {
  const float* image    = (const float*)d_in[0];
  const float* question = (const float*)d_in[1];
  const float* Wg1      = (const float*)d_in[2];
  const float* bg1      = (const float*)d_in[3];
  const float* Wg2      = (const float*)d_in[4];
  const float* bg2      = (const float*)d_in[5];
  const float* Wf1      = (const float*)d_in[6];
  const float* bf1      = (const float*)d_in[7];
  const float* Wf2      = (const float*)d_in[8];
  const float* bf2      = (const float*)d_in[9];
  float* out = (float*)d_out;

  u16*   wsb  = (u16*)d_ws;
  u16*   Lqp  = wsb + LQ_U16;
  u16*   Rp   = wsb + R_U16;
  u16*   Bswz = wsb + BS_U16;
  float* Sp   = (float*)((char*)d_ws + S_BYTE);

  prep<<<512, 256, 0, stream>>>(image, question, Wg1, bg1, Wg2,
                                Lqp, Rp, Sp, Bswz);
  pair_gemm<<<512, 512, 0, stream>>>(Lqp, Rp, Bswz, bg2, Sp);
  final_mlp<<<NB, 256, 0, stream>>>(Sp, Wf1, bf1, Wf2, bf2, out);
}

// Round 22
// 105.552 us; speedup vs baseline: 1.2284x; 1.2259x over previous
//
#include <hip/hip_runtime.h>
#include <hip/hip_bf16.h>

// Problem constants
#define NB   32      // batch
#define NC   24      // image channels
#define ND   12      // spatial
#define NN   144     // ND*ND objects
#define QD   11
#define GH   256
#define FOUT 10

typedef unsigned short u16;
typedef _Float16 f16;
typedef __attribute__((ext_vector_type(8))) _Float16 f16x8;
typedef __attribute__((ext_vector_type(4))) float f32x4;

// Workspace layout (u16 units unless noted):
//   Lqh  u16 [32][144][256]  off 0          (= L + q@Wg1_q + bg1, f16)
//   Rh   u16 [32][144][256]  off 1179648
//   Bswz u16 [128][64][8]    off 2359296    (16x16x32 B-fragment order, f16)
//   S    f32 [32][256]       byte-off 4849664
#define LQ_U16  0
#define R_U16   1179648
#define BS_U16  2359296
#define S_BYTE  4849664

__device__ inline u16 f2h(float f) {
  f16 h = (f16)f;
  return *reinterpret_cast<u16*>(&h);
}

// ---------------------------------------------------------------------------
// prep v2 (r17-proven): Wg1 in registers; blocks [0,256) projections (f16
// out), blocks [256,512): Wg2 -> f16 B-fragment swizzle + zero S.
// ---------------------------------------------------------------------------
__global__ __launch_bounds__(256) void prep(const float* __restrict__ image,
                                            const float* __restrict__ question,
                                            const float* __restrict__ Wg1,
                                            const float* __restrict__ bg1,
                                            const float* __restrict__ Wg2,
                                            u16* __restrict__ Lq,
                                            u16* __restrict__ R,
                                            float* __restrict__ S,
                                            u16* __restrict__ Bswz) {
  int blk = blockIdx.x;
  int h   = threadIdx.x;
  if (blk < 256) {
    const int quarter = blk & 3;
    const int b       = (blk >> 2) & 31;
    const int which   = blk >> 7;
    float Wl[NC + 2];
#pragma unroll
    for (int r = 0; r < NC + 2; ++r)
      Wl[r] = Wg1[(which * (NC + 2) + r) * GH + h];
    float qacc = 0.f;
    if (which == 0) {
      qacc = bg1[h];
#pragma unroll
      for (int tq = 0; tq < QD; ++tq)
        qacc += question[b * QD + tq] * Wg1[(2 * (NC + 2) + tq) * GH + h];
    }
    const float* img = image + b * (NC * NN);
    u16* dst = (which == 0 ? Lq : R) + b * NN * GH + h;
    const float inv = 1.0f / (ND - 1);
#pragma unroll 4
    for (int p = quarter * 36; p < quarter * 36 + 36; ++p) {
      float acc = qacc;
#pragma unroll
      for (int c = 0; c < NC; ++c) acc += img[c * NN + p] * Wl[c];
      int i = p / ND, j = p - i * ND;
      acc += (j * inv) * Wl[24];
      acc += (i * inv) * Wl[25];
      dst[p * GH] = f2h(acc);
    }
  } else {
    int tid = (blk - 256) * 256 + h;   // 0..65535
    int e   = tid & 7;
    int l   = (tid >> 3) & 63;
    int fid = tid >> 9;
    int kt  = fid >> 4, nt = fid & 15;
    int k = kt * 32 + ((l >> 4) << 3) + e;
    int n = (nt << 4) + (l & 15);
    Bswz[tid] = f2h(Wg2[k * GH + n]);
    if (tid < NB * GH) S[tid] = 0.f;
  }
}

// ---------------------------------------------------------------------------
// MFMA pair GEMM v19 (SESSION BEST, reverted from v20/v21 spill probes).
// F16 end-to-end: build math is v_pk_add_f16 + v_pk_max_f16 (8 VALU per
// 8 elems vs 36 for the bf16 decode path). f16 mantissa 10 bit > bf16 8 bit;
// MFMA accumulates f32 (mfma_f32_16x16x32_f16, same rate as bf16).
// Block = 512 thr (8 waves, 2m x 4n), tile = 128 pairs x 256 cols.
// Per tile: [build | bar | mma + epi | bar]; XOR-swizzled A (0 conflicts);
// setprio around MFMA. Grid = 512 blocks (2/CU) XCD-pinned; ~10 tiles each.
// Register budget: phase-disjoint lifetimes fit the 128-cap of (512,2) —
// v20/v21 proved ANY additional always-live prefetch state (even 32 regs)
// spills; the compiler's own B-pipelining uses the remaining headroom.
// ---------------------------------------------------------------------------
__global__ __launch_bounds__(512, 2) void pair_gemm(const u16* __restrict__ Lq,
                                                    const u16* __restrict__ R,
                                                    const u16* __restrict__ Bswz,
                                                    const float* __restrict__ bg2,
                                                    float* __restrict__ S) {
  const int bid = blockIdx.x;          // 0..511
  const int xcd = bid & 7;
  const int idx = bid >> 3;            // 0..63
  const int b   = xcd * 4 + (idx >> 4);
  const int bi  = idx & 15;            // 16 blocks per batch, 162 tiles
  const int t0  = bi * 10 + (bi < 2 ? bi : 2);
  const int cnt = 10 + (bi < 2 ? 1 : 0);

  // [kt 8][mf 8][lane 64][8 f16] = 64 KB
  __shared__ __align__(16) u16 As[8 * 8 * 64 * 8];

  const int t = threadIdx.x;
  const int w = t >> 6, l = t & 63;
  const int wn = w & 3, wm = w >> 2;
  // builder role: row t>>2 (0..127), k-octet t&3
  const int brow = t >> 2;
  const int oc   = t & 3;
  const int mf_w   = brow >> 4;                              // 0..7
  const int lane_w = ((brow & 15) | (oc << 4)) ^ (oc << 1);  // 2-way (free)
  const int lane_r = l ^ (((l >> 4) & 3) << 1);

  const u16* Lbase = Lq + b * NN * GH;
  const u16* Rbase = R + b * NN * GH;
  const u16* Bl    = Bswz + l * 8;

  float bgv[4];
#pragma unroll
  for (int nt = 0; nt < 4; ++nt)
    bgv[nt] = bg2[(wn << 6) + (nt << 4) + (l & 15)];
  float ssum[4] = {0.f, 0.f, 0.f, 0.f};

  for (int tt = 0; tt < cnt; ++tt) {
    // ---- build phase: whole 128x256 tile into LDS (pk f16 math) ----
    {
      int p = (t0 + tt) * 128 + brow;
      int i = p / NN, j = p - i * NN;
      const u16* Lr = Lbase + i * GH + oc * 8;
      const u16* Rr = Rbase + j * GH + oc * 8;
#pragma unroll
      for (int half = 0; half < 2; ++half) {
        f16x8 lv[4], rv[4];
#pragma unroll
        for (int q = 0; q < 4; ++q) {
          lv[q] = *(const f16x8*)(Lr + ((half << 2) | q) * 32);
          rv[q] = *(const f16x8*)(Rr + ((half << 2) | q) * 32);
        }
#pragma unroll
        for (int q = 0; q < 4; ++q) {
          const int kt = (half << 2) | q;
          f16x8 s = lv[q] + rv[q];                       // v_pk_add_f16
          s = __builtin_elementwise_max(s, (f16x8)0.0f); // v_pk_max_f16
          *(f16x8*)&As[((((kt << 3) | mf_w) << 6) | lane_w) << 3] = s;
        }
      }
    }
    __syncthreads();

    // ---- MFMA phase ----
    f32x4 acc[4][4] = {};
#pragma unroll
    for (int kt = 0; kt < 8; ++kt) {
      f16x8 af[4];
#pragma unroll
      for (int mf = 0; mf < 4; ++mf)
        af[mf] = *(const f16x8*)
            &As[((((kt << 3) | (wm << 2) | mf) << 6) | lane_r) << 3];
      f16x8 bfr[4];
#pragma unroll
      for (int nt = 0; nt < 4; ++nt) {
        int fid = (kt << 4) | (wn << 2) | nt;
        bfr[nt] = *(const f16x8*)(Bl + ((size_t)fid << 9));
      }
      __builtin_amdgcn_s_setprio(1);
#pragma unroll
      for (int mf = 0; mf < 4; ++mf)
#pragma unroll
        for (int nt = 0; nt < 4; ++nt)
          acc[mf][nt] = __builtin_amdgcn_mfma_f32_16x16x32_f16(
              af[mf], bfr[nt], acc[mf][nt], 0, 0, 0);
      __builtin_amdgcn_s_setprio(0);
    }
    // epilogue: fold relu(acc + bg2) into running sums
#pragma unroll
    for (int nt = 0; nt < 4; ++nt) {
      float s = 0.f;
#pragma unroll
      for (int mf = 0; mf < 4; ++mf)
#pragma unroll
        for (int r = 0; r < 4; ++r) {
          float v = acc[mf][nt][r] + bgv[nt];
          s += v > 0.f ? v : 0.f;
        }
      ssum[nt] += s;
    }
    __syncthreads();
  }

  // Final reduce: C/D col = l&15; shfl-reduce rows, one atomic per col slice
  float* Sb = S + b * GH;
#pragma unroll
  for (int nt = 0; nt < 4; ++nt) {
    float s = ssum[nt];
    s += __shfl_xor(s, 16, 64);
    s += __shfl_xor(s, 32, 64);
    if (l < 16) atomicAdd(&Sb[(wn << 6) + (nt << 4) + l], s);
  }
}

// ---------------------------------------------------------------------------
// Final f-MLP: out = relu(S@Wf1+bf1)@Wf2+bf2. One block per batch.
// ---------------------------------------------------------------------------
__global__ __launch_bounds__(256) void final_mlp(const float* __restrict__ S,
                                                 const float* __restrict__ Wf1,
                                                 const float* __restrict__ bf1,
                                                 const float* __restrict__ Wf2,
                                                 const float* __restrict__ bf2,
                                                 float* __restrict__ out) {
  __shared__ float sS[GH];
  __shared__ float oS[GH];
  int b = blockIdx.x, h = threadIdx.x;
  sS[h] = S[b * GH + h];
  __syncthreads();
  float acc = bf1[h];
#pragma unroll 8
  for (int k = 0; k < GH; ++k) acc += sS[k] * Wf1[k * GH + h];
  oS[h] = acc > 0.f ? acc : 0.f;
  __syncthreads();
  if (h < FOUT) {
    float o = bf2[h];
#pragma unroll 8
    for (int k = 0; k < GH; ++k) o += oS[k] * Wf2[k * FOUT + h];
    out[b * FOUT + h] = o;
  }
}

extern "C" void kernel_launch(void* const* d_in, const int* in_sizes, int n_in,
                              void* d_out, int out_size, void* d_ws, size_t ws_size,
                              hipStream_t stream) {
  const float* image    = (const float*)d_in[0];
  const float* question = (const float*)d_in[1];
  const float* Wg1      = (const float*)d_in[2];
  const float* bg1      = (const float*)d_in[3];
  const float* Wg2      = (const float*)d_in[4];
  const float* bg2      = (const float*)d_in[5];
  const float* Wf1      = (const float*)d_in[6];
  const float* bf1      = (const float*)d_in[7];
  const float* Wf2      = (const float*)d_in[8];
  const float* bf2      = (const float*)d_in[9];
  float* out = (float*)d_out;

  u16*   wsb  = (u16*)d_ws;
  u16*   Lqp  = wsb + LQ_U16;
  u16*   Rp   = wsb + R_U16;
  u16*   Bswz = wsb + BS_U16;
  float* Sp   = (float*)((char*)d_ws + S_BYTE);

  prep<<<512, 256, 0, stream>>>(image, question, Wg1, bg1, Wg2,
                                Lqp, Rp, Sp, Bswz);
  pair_gemm<<<512, 512, 0, stream>>>(Lqp, Rp, Bswz, bg2, Sp);
  final_mlp<<<NB, 256, 0, stream>>>(Sp, Wf1, bf1, Wf2, bf2, out);
}